// Round 9
// baseline (268.394 us; speedup 1.0000x reference)
//
#include <hip/hip_runtime.h>
#include <hip/hip_bf16.h>
#include <stdint.h>

// Problem constants
#define B_    16
#define N_    577
#define C_    768
#define H_    12
#define M_    (B_*N_)     // 9232 rows
#define QKVN  (3*C_)      // 2304
#define NKEEP 403         // int(576*0.7)
#define KROWS (NKEEP+1)   // 404
#define VTLD  640         // vtbuf padded row length
#define PTLD  72          // Ptt row stride (ushorts)

typedef short s16x8 __attribute__((ext_vector_type(8)));
typedef float f32x4 __attribute__((ext_vector_type(4)));

__device__ __forceinline__ unsigned short f2bf(float x){
  unsigned int u = __float_as_uint(x);
  u += 0x7FFF + ((u >> 16) & 1);          // round-to-nearest-even
  return (unsigned short)(u >> 16);
}

// async global->LDS, 16B per lane; lds dest = wave-uniform base + lane*16
__device__ __forceinline__ void gld_lds16(const void* g, void* l){
  __builtin_amdgcn_global_load_lds(
      (const __attribute__((address_space(1))) unsigned int*)g,
      (__attribute__((address_space(3))) unsigned int*)l, 16, 0, 0);
}

// Generic XCD-panel tile mapping: xcd = L&7 owns m-panel [x*M9, x*M9+M9);
// tail m-tiles (>= 8*M9) distributed to match round-robin per-XCD counts (bijective).
template<int NT, int M9, int MTILES>
__device__ __forceinline__ void tile_map(int L, int& mt, int& nt){
  constexpr int NB = MTILES*NT;
  int x = L & 7, j = L >> 3;
  if(j < M9*NT){
    nt = j/M9; mt = x*M9 + (j - nt*M9);    // n-outer: M9 consecutive blocks share B-tile
  } else {
    int offt = 0;
    #pragma unroll
    for(int y=0;y<8;y++) if(y<x) offt += ((NB-1-y)>>3) + 1 - M9*NT;  // tail_y
    int ft = offt + (j - M9*NT);
    mt = 8*M9 + ft/NT;
    nt = ft - (ft/NT)*NT;
  }
}

// =============== fused prep: cvt_x | transpose Wqkv | transpose Wproj | qcls ===============
// Region split: cvt [0,6924) | WqkvT [6924,7356) | WprojT [7356,7500) | qcls [7500,7692)
__global__ __launch_bounds__(256) void k_prep(const float* __restrict__ x,
                       const float* __restrict__ Wqkv, const float* __restrict__ Wproj,
                       unsigned short* __restrict__ xb, unsigned short* __restrict__ wqkvT,
                       unsigned short* __restrict__ wprojT, float* __restrict__ qcls){
  __shared__ float tile[64][65];
  __shared__ float part[4][64];
  const int bid = blockIdx.x, t = threadIdx.x;
  if(bid < 6924){
    int i = bid*256 + t;
    float4 v = ((const float4*)x)[i];
    ushort4 o; o.x=f2bf(v.x); o.y=f2bf(v.y); o.z=f2bf(v.z); o.w=f2bf(v.w);
    ((ushort4*)xb)[i] = o;
  } else if(bid < 7500){
    const float* in; unsigned short* out; int R, CC, bx, by;
    if(bid < 7356){ int r = bid - 6924; bx = r % 36; by = r / 36; in = Wqkv;  out = wqkvT;  R = 768; CC = 2304; }
    else          { int r = bid - 7356; bx = r % 12; by = r / 12; in = Wproj; out = wprojT; R = 768; CC = 768;  }
    int r0 = by*64, c0 = bx*64;
    int tx = t & 63, ty = t >> 6;
    #pragma unroll
    for(int i=0;i<16;i++){
      int r = ty + i*4;
      tile[r][tx] = in[(size_t)(r0+r)*CC + c0 + tx];
    }
    __syncthreads();
    #pragma unroll
    for(int i=0;i<16;i++){
      int c = ty + i*4;
      out[(size_t)(c0+c)*R + r0 + tx] = f2bf(tile[tx][c]);
    }
  } else {
    int r = bid - 7500;
    const int b = r / 12, j0 = (r % 12)*64;
    float* xs = &tile[0][0];
    const float* xr = x + (size_t)b*577*768;
    xs[t] = xr[t]; xs[t+256] = xr[t+256]; xs[t+512] = xr[t+512];
    __syncthreads();
    const int jl = t & 63, cs = t >> 6;
    float acc = 0.f;
    const float* wp = Wqkv + (size_t)(cs*192)*2304 + j0 + jl;
    #pragma unroll 4
    for(int c=0;c<192;c++){ acc += xs[cs*192+c] * wp[0]; wp += 2304; }
    part[cs][jl] = acc;
    __syncthreads();
    if(t < 64) qcls[b*768 + j0 + t] = part[0][t]+part[1][t]+part[2][t]+part[3][t];
  }
}

// ---------------- GEMM epilogue (shared): FUSEV V-transpose or plain C write ----------------
template<int LDC_, bool BF16OUT, bool FUSEV>
__device__ __forceinline__ void gemm_epilogue(f32x4 (&acc)[4][4], int m0, int n0,
                          int wm, int wn, int lq, int lr, void* Cout,
                          const float* bias, int Mdim, unsigned short* vtbuf){
  if(FUSEV && n0 >= 1536){
    #pragma unroll
    for(int it=0;it<4;it++){
      int tok0 = m0 + wm*64 + it*16 + lq*4;
      #pragma unroll
      for(int jt=0;jt<4;jt++){
        int vrow = (n0 - 1536) + wn*64 + jt*16 + lr;
        ushort4 pk; unsigned short* pks = (unsigned short*)&pk;
        #pragma unroll
        for(int r=0;r<4;r++) pks[r] = f2bf(acc[it][jt][r]);
        int b0 = tok0/577, t0 = tok0 - b0*577;
        if(tok0 + 3 < M_ && t0 + 3 < 577){
          *(ushort4*)&vtbuf[(size_t)(b0*768 + vrow)*VTLD + t0] = pk;
        } else {
          #pragma unroll
          for(int r=0;r<4;r++){
            int tg = tok0 + r;
            if(tg < M_){
              int bb = tg/577, tt = tg - bb*577;
              vtbuf[(size_t)(bb*768 + vrow)*VTLD + tt] = pks[r];
            }
          }
        }
      }
    }
  } else {
    #pragma unroll
    for(int it=0;it<4;it++){
      #pragma unroll
      for(int r=0;r<4;r++){
        int row = m0 + wm*64 + it*16 + lq*4 + r;
        if(row < Mdim){
          #pragma unroll
          for(int jt=0;jt<4;jt++){
            int col = n0 + wn*64 + jt*16 + lr;
            float v = acc[it][jt][r];
            if constexpr (BF16OUT)
              ((unsigned short*)Cout)[(size_t)row*LDC_ + col] = f2bf(v);
            else
              ((float*)Cout)[(size_t)row*LDC_ + col] = v + bias[col];
          }
        }
      }
    }
  }
}

// ---------------- GEMM: 128x128 tile, BK=64 DOUBLE-buffer, counted vmcnt ----------------
// (r8 proven: 50.3us on GEMM1, 0 bank conflicts.) Used for BOTH GEMM1 (FUSEV) and GEMM2.
// Swizzle: source col pre-XORed ((t&7)^((t>>3)&7))<<3; read chunk (ks*4+lq)^(row&7).
// Schedule per kt (slot s=kt&1): READ 16 ds_read (slot s); lgkmcnt(0)+sched_barrier;
// barrier; STAGE(kt+2 -> s); setprio MFMA x32; vmcnt(8) [tile kt+1 landed]; barrier.
template<int LDC_, bool BF16OUT, bool FUSEV, int NT>
__global__ __launch_bounds__(256) void k_gemm_db(const unsigned short* __restrict__ A,
                          const unsigned short* __restrict__ Bt,
                          void* __restrict__ Cout,
                          const float* __restrict__ bias, int Mdim,
                          unsigned short* __restrict__ vtbuf){
  __shared__ __align__(16) unsigned short As[2][128*64];  // 32 KB
  __shared__ __align__(16) unsigned short Bs[2][128*64];  // 32 KB
  const int t = threadIdx.x;
  const int w = t>>6, l = t&63, lq = l>>4, lr = l&15;
  const int wm = w>>1, wn = w&1;
  int mt, nt; tile_map<NT, 9, 73>(blockIdx.x, mt, nt);
  const int m0 = mt*128, n0 = nt*128;
  const int srow = t>>3;
  const int csw  = (((t&7) ^ ((t>>3)&7))<<3);
  const unsigned short* gA[4]; const unsigned short* gB[4];
  #pragma unroll
  for(int i=0;i<4;i++){
    int ra = m0 + i*32 + srow; if(ra >= Mdim) ra = Mdim-1;
    gA[i] = A  + (size_t)ra*768 + csw;
    gB[i] = Bt + (size_t)(n0 + i*32 + srow)*768 + csw;
  }
  const int rxa = lr&7;
  f32x4 acc[4][4] = {};

#define STAGE_DB(KT, S) do{ \
  unsigned short* dA_ = &As[(S)][w*512]; \
  unsigned short* dB_ = &Bs[(S)][w*512]; \
  _Pragma("unroll") \
  for(int i_=0;i_<4;i_++){ \
    gld_lds16(gA[i_] + (size_t)(KT)*64, dA_ + i_*2048); \
    gld_lds16(gB[i_] + (size_t)(KT)*64, dB_ + i_*2048); \
  } \
}while(0)

  STAGE_DB(0,0);
  STAGE_DB(1,1);
  asm volatile("s_waitcnt vmcnt(8)" ::: "memory");
  __builtin_amdgcn_s_barrier();

  for(int kt=0; kt<12; ++kt){
    const int s = kt&1;
    s16x8 af[4][2], bfr[4][2];
    #pragma unroll
    for(int ks=0;ks<2;ks++){
      const int cx = ((ks*4 + lq) ^ rxa) << 3;
      #pragma unroll
      for(int it=0;it<4;it++) af[it][ks]  = *(const s16x8*)&As[s][(wm*64+it*16+lr)*64 + cx];
      #pragma unroll
      for(int jt=0;jt<4;jt++) bfr[jt][ks] = *(const s16x8*)&Bs[s][(wn*64+jt*16+lr)*64 + cx];
    }
    asm volatile("s_waitcnt lgkmcnt(0)" ::: "memory");
    __builtin_amdgcn_sched_barrier(0);
    __builtin_amdgcn_s_barrier();
    if(kt<10) STAGE_DB(kt+2, s);
    __builtin_amdgcn_s_setprio(1);
    #pragma unroll
    for(int ks=0;ks<2;ks++)
      #pragma unroll
      for(int it=0;it<4;it++)
        #pragma unroll
        for(int jt=0;jt<4;jt++)
          acc[it][jt] = __builtin_amdgcn_mfma_f32_16x16x32_bf16(af[it][ks], bfr[jt][ks], acc[it][jt], 0,0,0);
    __builtin_amdgcn_s_setprio(0);
    if(kt<10){
      asm volatile("s_waitcnt vmcnt(8)" ::: "memory");
    } else if(kt==10){
      asm volatile("s_waitcnt vmcnt(0)" ::: "memory");
    }
    __builtin_amdgcn_s_barrier();
  }
  gemm_epilogue<LDC_, BF16OUT, FUSEV>(acc, m0, n0, wm, wn, lq, lr, Cout, bias, Mdim, vtbuf);
#undef STAGE_DB
}

// ---------------- fused flash attention (r5 T14 form, kept) ----------------
__global__ __launch_bounds__(256,4) void k_attn(const unsigned short* __restrict__ qkv,
                                                const unsigned short* __restrict__ vtbuf,
                                                unsigned short* __restrict__ aout){
  __shared__ __align__(16) unsigned short Ks[64*64];
  __shared__ __align__(16) unsigned short Vt[64*64];
  __shared__ __align__(16) unsigned short Ptt[128*PTLD];
  __shared__ float Ls[4][2][16][4];
  const int blk = blockIdx.x;
  const int bh = blk % 192, qt = blk / 192;
  const int b = bh / 12, h = bh % 12;
  const int t = threadIdx.x, w = t>>6, l = t&63, lq = l>>4, lr = l&15;
  const size_t base = (size_t)(b*577)*2304 + h*64;
  const int q0 = qt*128;
  s16x8 bq[2][2];
  #pragma unroll
  for(int it=0;it<2;it++){
    int qrow = q0 + w*32 + it*16 + lr; if(qrow > 576) qrow = 576;
    #pragma unroll
    for(int ks=0;ks<2;ks++)
      bq[it][ks] = *(const s16x8*)&qkv[base + (size_t)qrow*2304 + ks*32 + lq*8];
  }
  const int srow = w*8 + (l>>3);
  const int cswz8 = (((l&7) ^ (l>>3)) << 3);
  unsigned short* ldsK = Ks + w*512 + l*8;
  unsigned short* ldsV = Vt + w*512 + l*8;
  const unsigned short* gVbase = vtbuf + (size_t)(bh*64)*VTLD + cswz8;

  f32x4 acc_o[2][4] = {};
  float lsum[2] = {0.f, 0.f};
  const float CEXP = 0.18033688011112043f;              // 0.125 * log2(e)

  s16x8 kreg0, kreg1, vreg0, vreg1;
  auto stage_issue = [&](int tt){
    const int j0i = tt*64;
    int kr0 = j0i + srow;      if(kr0 > 576) kr0 = 576;
    int kr1 = j0i + 32 + srow; if(kr1 > 576) kr1 = 576;
    kreg0 = *(const s16x8*)(qkv + base + 768 + (size_t)kr0*2304 + cswz8);
    kreg1 = *(const s16x8*)(qkv + base + 768 + (size_t)kr1*2304 + cswz8);
    vreg0 = *(const s16x8*)(gVbase + (size_t)srow*VTLD + j0i);
    vreg1 = *(const s16x8*)(gVbase + (size_t)(32 + srow)*VTLD + j0i);
  };

  stage_issue(0);
  for(int g=0; g<10; ++g){
    const int j0 = g*64;
    const bool edge = (g == 9);
    *(s16x8*)(ldsK)        = kreg0;
    *(s16x8*)(ldsK + 2048) = kreg1;
    *(s16x8*)(ldsV)        = vreg0;
    *(s16x8*)(ldsV + 2048) = vreg1;
    asm volatile("s_waitcnt lgkmcnt(0)" ::: "memory");
    __builtin_amdgcn_s_barrier();
    __builtin_amdgcn_sched_barrier(0);
    if(g < 9) stage_issue(g+1);

    f32x4 accs[2][4] = {};
    #pragma unroll
    for(int ks=0;ks<2;ks++){
      s16x8 ak[4];
      #pragma unroll
      for(int jt=0;jt<4;jt++){
        int j = jt*16 + lr;
        ak[jt] = *(const s16x8*)&Ks[j*64 + (((4*ks+lq) ^ (j&7))<<3)];
      }
      #pragma unroll
      for(int it=0;it<2;it++)
        #pragma unroll
        for(int jt=0;jt<4;jt++)
          accs[it][jt] = __builtin_amdgcn_mfma_f32_16x16x32_bf16(ak[jt], bq[it][ks], accs[it][jt], 0,0,0);
    }
    #pragma unroll
    for(int it=0;it<2;it++){
      int qlocal = w*32 + it*16 + lr;
      #pragma unroll
      for(int jt=0;jt<4;jt++){
        ushort4 pk;
        unsigned short* pks = (unsigned short*)&pk;
        #pragma unroll
        for(int r=0;r<4;r++){
          float p = exp2f(accs[it][jt][r] * CEXP);
          if(edge){ if(j0 + jt*16 + lq*4 + r > 576) p = 0.f; }
          lsum[it] += p;
          pks[r] = f2bf(p);
        }
        *(ushort4*)&Ptt[qlocal*PTLD + jt*16 + lq*4] = pk;
      }
    }
    #pragma unroll
    for(int ks=0;ks<2;ks++){
      s16x8 ap[2], bv[4];
      #pragma unroll
      for(int it=0;it<2;it++)
        ap[it] = *(const s16x8*)&Ptt[(w*32+it*16+lr)*PTLD + ks*32 + lq*8];
      #pragma unroll
      for(int dt=0;dt<4;dt++){
        int d = dt*16 + lr;
        bv[dt] = *(const s16x8*)&Vt[d*64 + (((4*ks+lq) ^ (d&7))<<3)];
      }
      #pragma unroll
      for(int it=0;it<2;it++)
        #pragma unroll
        for(int dt=0;dt<4;dt++)
          acc_o[it][dt] = __builtin_amdgcn_mfma_f32_16x16x32_bf16(ap[it], bv[dt], acc_o[it][dt], 0,0,0);
    }
    asm volatile("s_waitcnt lgkmcnt(0)" ::: "memory");
    __builtin_amdgcn_s_barrier();
    __builtin_amdgcn_sched_barrier(0);
  }

  #pragma unroll
  for(int it=0;it<2;it++) Ls[w][it][lr][lq] = lsum[it];
  #pragma unroll
  for(int it=0;it<2;it++){
    #pragma unroll
    for(int r=0;r<4;r++){
      int n = q0 + w*32 + it*16 + lq*4 + r;
      if(n <= 576){
        int q16 = lq*4 + r;
        float lt = Ls[w][it][q16][0] + Ls[w][it][q16][1] + Ls[w][it][q16][2] + Ls[w][it][q16][3];
        float inv = 1.f / lt;
        #pragma unroll
        for(int dt=0;dt<4;dt++)
          aout[(size_t)(b*577+n)*768 + h*64 + dt*16 + lr] = f2bf(acc_o[it][dt][r]*inv);
      }
    }
  }
}

// ---------------- fp32 top-k path ----------------
__global__ void k_u(const float* __restrict__ Wqkv, const float* __restrict__ qcls,
                    float* __restrict__ u){
  int h = blockIdx.x, b = blockIdx.y, c = threadIdx.x;  // 768 threads
  const float* qc = qcls + b*768 + h*64;
  const float* wr = Wqkv + (size_t)c*2304 + 768 + h*64;
  float acc = 0.f;
  #pragma unroll
  for(int d=0;d<64;d++) acc += wr[d]*qc[d];
  u[(size_t)(b*12+h)*768 + c] = acc;
}
// r9: LDS-staged u. Block = 16 tokens (4 waves x 4 serial); u[b] (36 KB) staged once
// per block -> L2 traffic 360 MB -> ~21 MB. Per-token arithmetic + shfl reduce order
// byte-identical to the 1-wave version -> identical fp32 ranks for top-k.
__global__ __launch_bounds__(256) void k_attw(const float* __restrict__ x, const float* __restrict__ u,
                       float* __restrict__ attw){
  __shared__ float us[12*768];                // 36 KB
  const int b = blockIdx.x, g0 = blockIdx.y*16;
  const int t = threadIdx.x, w = t>>6, lane = t&63;
  const float* ub = u + (size_t)b*12*768;
  for(int i=t; i<12*768; i+=256) us[i] = ub[i];
  __syncthreads();
  #pragma unroll
  for(int sd=0; sd<4; ++sd){
    int m = g0 + w*4 + sd;                    // wave-uniform token index
    if(m <= 576){
      const float* xr = x + (size_t)(b*577+m)*768;
      float part[12];
      #pragma unroll
      for(int h=0;h<12;h++) part[h]=0.f;
      #pragma unroll
      for(int i=0;i<12;i++){
        float xv = xr[i*64 + lane];
        #pragma unroll
        for(int h=0;h<12;h++) part[h] += xv * us[h*768 + i*64 + lane];
      }
      float s = 0.f;
      #pragma unroll
      for(int h=0;h<12;h++){
        float v = part[h];
        #pragma unroll
        for(int off=32; off; off>>=1) v += __shfl_xor(v, off);
        s += fabsf(v);
      }
      if(lane==0) attw[b*577 + m] = 0.125f * s;
    }
  }
}
// ---- fused top-k + keep_index broadcast write. r9: grid (16,8) - every y-block
// redundantly computes the (deterministic) rank/sidx; each writes 1/8 of out2.
__global__ void k_topk_fill(const float* __restrict__ attw, float* __restrict__ out2){
  __shared__ float sw[576];
  __shared__ int wtot[9];
  __shared__ int sidx[KROWS];
  int b = blockIdx.x, t = threadIdx.x;     // 576 threads
  float wv = attw[b*577 + 1 + t];
  sw[t] = wv;
  __syncthreads();
  int rank = 0;
  for(int j=0;j<576;j++){
    float wj = sw[j];
    rank += (wj > wv) || (wj == wv && j < t);
  }
  bool kept = rank < NKEEP;
  unsigned long long mask = __ballot(kept);
  int wid = t>>6, lane = t&63;
  int pos = __popcll(mask & ((1ull<<lane)-1ull));
  if(lane==0) wtot[wid] = __popcll(mask);
  __syncthreads();
  int off0 = 0;
  for(int q=0;q<wid;q++) off0 += wtot[q];
  if(kept) sidx[1 + off0 + pos] = t+1;
  if(t==0) sidx[0] = 0;
  __syncthreads();
  // this y-block writes rows [y*9696, (y+1)*9696) of the 77568 float4s (KROWS*192)
  const int y0 = blockIdx.y * 9696;
  float4* o4 = (float4*)out2 + (size_t)b*KROWS*192;
  for(int i = y0 + t; i < y0 + 9696; i += 576){
    float v = (float)sidx[i/192];
    o4[i] = make_float4(v,v,v,v);
  }
}

extern "C" void kernel_launch(void* const* d_in, const int* in_sizes, int n_in,
                              void* d_out, int out_size, void* d_ws, size_t ws_size,
                              hipStream_t stream){
  const float* x     = (const float*)d_in[0];
  const float* Wqkv  = (const float*)d_in[1];
  const float* Wproj = (const float*)d_in[2];
  const float* bias  = (const float*)d_in[3];
  float* out  = (float*)d_out;
  float* out2 = out + (size_t)M_*768;      // keep_index chunk (float32)

  char* ws = (char*)d_ws;
  size_t off = 0;
  auto alloc = [&](size_t bytes)->void*{ void* p = ws + off; off += (bytes + 255) & ~(size_t)255; return p; };
  unsigned short* xb     = (unsigned short*)alloc((size_t)M_*768*2);
  unsigned short* wqkvT  = (unsigned short*)alloc((size_t)QKVN*768*2);
  unsigned short* wprojT = (unsigned short*)alloc((size_t)768*768*2);
  unsigned short* qkvb   = (unsigned short*)alloc((size_t)M_*QKVN*2);
  unsigned short* aoutb  = (unsigned short*)alloc((size_t)M_*768*2);
  unsigned short* vtbuf  = (unsigned short*)alloc((size_t)192*64*VTLD*2);
  float* qcls   = (float*)alloc((size_t)16*768*4);
  float* u      = (float*)alloc((size_t)16*12*768*4);
  float* attw   = (float*)alloc((size_t)16*577*4);

  // fused prep: cvt_x | transpose Wqkv | transpose Wproj | qcls  (7692 blocks)
  k_prep<<<7692, 256, 0, stream>>>(x, Wqkv, Wproj, xb, wqkvT, wprojT, qcls);
  // QKV GEMM (bf16 out; V-tiles transposed into vtbuf). BK=64 dbuf, counted vmcnt.
  k_gemm_db<QKVN, true, true, 18><<<73*18, 256, 0, stream>>>(xb, wqkvT, qkvb, nullptr, M_, vtbuf);
  // fp32 top-k weight path
  k_u<<<dim3(12,16), 768, 0, stream>>>(Wqkv, qcls, u);
  k_attw<<<dim3(16,37), 256, 0, stream>>>(x, u, attw);
  k_topk_fill<<<dim3(16,8), 576, 0, stream>>>(attw, out2);
  // attention + out-proj (dbuf template for GEMM2 as well)
  k_attn<<<960, 256, 0, stream>>>(qkvb, vtbuf, aoutb);
  k_gemm_db<768, false, false, 6><<<73*6, 256, 0, stream>>>(aoutb, wprojT, out, bias, M_, nullptr);
}